// Round 12
// baseline (2412.332 us; speedup 1.0000x reference)
//
#include <hip/hip_runtime.h>
#include <math.h>

#define NPTS 16384
#define NBATCH 8
#define CIN 128
#define COUT 256
#define NP 1024
#define NS 32

#define NCELL 512     // 8x8x8 Morton cells
#define FPS_T 512     // 8 waves, 2/SIMD
#define NSLOT 32      // slots (tiles) per wave; tile = 64 consecutive sorted pts

// ---------------- spatial sort preprocessing ----------------
__device__ __forceinline__ int cell_of(float x, float y, float z)
{
  int ix = (int)(x * 8.0f); ix = ix < 0 ? 0 : (ix > 7 ? 7 : ix);
  int iy = (int)(y * 8.0f); iy = iy < 0 ? 0 : (iy > 7 ? 7 : iy);
  int iz = (int)(z * 8.0f); iz = iz < 0 ? 0 : (iz > 7 ? 7 : iz);
  int m = 0;
#pragma unroll
  for (int b = 0; b < 3; ++b)
    m |= (((ix >> b) & 1) << (3 * b)) | (((iy >> b) & 1) << (3 * b + 1))
       | (((iz >> b) & 1) << (3 * b + 2));
  return m;
}

__global__ void zero_hist_kernel(int* __restrict__ hist)
{
  hist[blockIdx.x * NCELL + threadIdx.x] = 0;
}

__global__ void hist_kernel(const float* __restrict__ xyz, int* __restrict__ hist)
{
  const int i = blockIdx.x * 256 + threadIdx.x;
  const int b = i >> 14, n = i & (NPTS - 1);
  const float* p = xyz + ((size_t)b * NPTS + n) * 3;
  atomicAdd(&hist[b * NCELL + cell_of(p[0], p[1], p[2])], 1);
}

__global__ void scan_kernel(const int* __restrict__ hist, int* __restrict__ cursor)
{
  __shared__ int s[NCELL];
  const int b = blockIdx.x, t = threadIdx.x;
  const int h = hist[b * NCELL + t];
  s[t] = h;
  __syncthreads();
  for (int off = 1; off < NCELL; off <<= 1) {
    const int v = (t >= off) ? s[t - off] : 0;
    __syncthreads();
    s[t] += v;
    __syncthreads();
  }
  cursor[b * NCELL + t] = s[t] - h;   // exclusive
}

// sxy2S: (x,y) by sorted pos; szS: z by sorted pos; plS: packed tie-break key
// (invpid<<14 | spos) by sorted pos (u32) — precomputed so FPS never touches si.
__global__ void scatter_kernel(const float* __restrict__ xyz, int* __restrict__ cursor,
                               float2* __restrict__ sxy2S, float* __restrict__ szS,
                               unsigned* __restrict__ plS)
{
  const int i = blockIdx.x * 256 + threadIdx.x;
  const int b = i >> 14, n = i & (NPTS - 1);
  const float* p = xyz + ((size_t)b * NPTS + n) * 3;
  const float x = p[0], y = p[1], z = p[2];
  const int pos = atomicAdd(&cursor[b * NCELL + cell_of(x, y, z)], 1);
  const size_t o = (size_t)b * NPTS + pos;
  sxy2S[o] = make_float2(x, y);
  szS[o] = z;
  plS[o] = ((unsigned)(n ^ 0x3FFF) << 14) | (unsigned)pos;
}

// ---------------- DPP helpers ----------------
template <int CTRL>
__device__ __forceinline__ void dpp_max64(unsigned& hi, unsigned& lo)
{
  const unsigned ohi = (unsigned)__builtin_amdgcn_update_dpp((int)hi, (int)hi, CTRL, 0xF, 0xF, false);
  const unsigned olo = (unsigned)__builtin_amdgcn_update_dpp((int)lo, (int)lo, CTRL, 0xF, 0xF, false);
  const bool t = (ohi > hi) || (ohi == hi && olo > lo);
  hi = t ? ohi : hi;
  lo = t ? olo : lo;
}
template <int CTRL>
__device__ __forceinline__ float dppmaxf(float v)
{
  const float o = __uint_as_float((unsigned)__builtin_amdgcn_update_dpp(
      (int)__float_as_uint(v), (int)__float_as_uint(v), CTRL, 0xF, 0xF, false));
  return fmaxf(v, o);
}
template <int CTRL>
__device__ __forceinline__ float dppminf(float v)
{
  const float o = __uint_as_float((unsigned)__builtin_amdgcn_update_dpp(
      (int)__float_as_uint(v), (int)__float_as_uint(v), CTRL, 0xF, 0xF, false));
  return fminf(v, o);
}
#define RED6F(v) v = dppmaxf<0x111>(v); v = dppmaxf<0x112>(v); v = dppmaxf<0x114>(v); \
                 v = dppmaxf<0x118>(v); v = dppmaxf<0x142>(v); v = dppmaxf<0x143>(v);
#define RED6FN(v) v = dppminf<0x111>(v); v = dppminf<0x112>(v); v = dppminf<0x114>(v); \
                  v = dppminf<0x118>(v); v = dppminf<0x142>(v); v = dppminf<0x143>(v);
#define RED64(h, l) dpp_max64<0x111>(h, l); dpp_max64<0x112>(h, l); \
                    dpp_max64<0x114>(h, l); dpp_max64<0x118>(h, l); \
                    dpp_max64<0x142>(h, l); dpp_max64<0x143>(h, l);

// ---------------- FPS ----------------
// 1 block/batch, 512 thr (8 waves, 2/SIMD) — HALF the waves of rounds 7-11:
// those were issue-bound on fixed per-wave work (test+combine+slot) x 16.
// Tile (w,j) = 64 consecutive sorted pts, 32 tiles/wave; ONE 32-lane test +
// ballot covers all of a wave's tiles. Per-tile exact keys (max|pl) cached in
// LDS thL/tlL[w][j] (conflict-free layout), recomputed only on update (fused
// RED64). Per-tile winner z in tzL -> per-wave redz -> combine is LDS-only.
// dist[32] registers, static access only. Tie-break exact everywhere.
__global__ __launch_bounds__(FPS_T)
void fps_kernel(const float* __restrict__ xyz,
                const float2* __restrict__ sxy2S, const float* __restrict__ szS,
                const unsigned* __restrict__ plS, int* __restrict__ fps_idx)
{
#pragma clang fp contract(off)
  __shared__ float2 XY[NPTS];                   // 128 KB, sorted order
  __shared__ unsigned thL[8][NSLOT];            // tile key hi (maxdist bits)
  __shared__ unsigned tlL[8][NSLOT];            // tile key lo (invpid<<14|spos)
  __shared__ float    tzL[8][NSLOT];            // tile winner z
  __shared__ float    tb[8][NSLOT][6];          // tile bboxes (init only)
  __shared__ unsigned long long redk[2][8];
  __shared__ float    redz[2][8];
  const int b = blockIdx.x;
  const int t = threadIdx.x;
  const int lane = t & 63, w = t >> 6;          // 8 waves
  const int l32 = lane & 31;
  const float* __restrict__ X = xyz + (size_t)b * NPTS * 3;
  const float* __restrict__ ZS = szS + (size_t)b * NPTS;
  const unsigned* __restrict__ PS = plS + (size_t)b * NPTS;
  const float2* __restrict__ XYS = sxy2S + (size_t)b * NPTS;

  float dist[NSLOT];
#pragma unroll
  for (int j = 0; j < NSLOT; ++j) {
    const int sp = (j << 9) + t;                // sorted pos owned by (j,t)
    const float2 v = XYS[sp];                   // coalesced
    XY[sp] = v;                                 // conflict-free ds_write_b64
    const float zz = ZS[sp];
    const unsigned pp = PS[sp];
    dist[j] = 1e10f;
    // tile (w,j) bbox + initial key (uniform dist -> winner = max pl)
    float xn = v.x, xx = v.x, yn = v.y, yx = v.y, zn = zz, zx = zz;
    RED6FN(xn) RED6F(xx) RED6FN(yn) RED6F(yx) RED6FN(zn) RED6F(zx)
    unsigned kh0 = __float_as_uint(1e10f), kl0 = pp;
    RED64(kh0, kl0)
    const unsigned skh = (unsigned)__builtin_amdgcn_readlane((int)kh0, 63);
    const unsigned skl = (unsigned)__builtin_amdgcn_readlane((int)kl0, 63);
    if (pp == skl) tzL[w][j] = zz;              // unique lane (pl unique)
    if (lane == 63) {
      tb[w][j][0] = xn; tb[w][j][1] = xx; tb[w][j][2] = yn;
      tb[w][j][3] = yx; tb[w][j][4] = zn; tb[w][j][5] = zx;
      thL[w][j] = skh; tlL[w][j] = skl;
    }
  }
  __syncthreads();
  // every lane caches the bbox of tile (w, lane&31) in registers
  const float bxn = tb[w][l32][0], bxx = tb[w][l32][1];
  const float byn = tb[w][l32][2], byx = tb[w][l32][3];
  const float bzn = tb[w][l32][4], bzx = tb[w][l32][5];

  unsigned wkh = 0, wkl = 0;                    // cached wave key
  float zc = 0.0f;                              // cached wave winner z
  {   // initial wave key from LDS tile keys
    unsigned h = thL[w][l32], l2 = tlL[w][l32];
    RED64(h, l2)
    wkh = (unsigned)__builtin_amdgcn_readlane((int)h, 63);
    wkl = (unsigned)__builtin_amdgcn_readlane((int)l2, 63);
    zc = tzL[w][(wkl & 0x3FFFu) >> 9];
  }

  int cur = 0;
  float lx = X[0], ly = X[1], lz = X[2];

  for (int k = 0; k < NP; ++k) {
    if (t == 0) fps_idx[b * NP + k] = cur;

    // lane tests tile (w, lane&31) against its own cached max (exact skip)
    const float th = __uint_as_float(thL[w][l32]);
    const float ddx = fmaxf(fmaxf(bxn - lx, lx - bxx), 0.0f);
    const float ddy = fmaxf(fmaxf(byn - ly, ly - byx), 0.0f);
    const float ddz = fmaxf(fmaxf(bzn - lz, lz - bzx), 0.0f);
    const float db2 = ((ddx * ddx) + (ddy * ddy)) + (ddz * ddz);
    const bool act = db2 <= th * 1.00001f;
    const unsigned msk = __builtin_amdgcn_readfirstlane(
        (unsigned)__ballot(act));               // lanes 32-63 mirror 0-31

    if (msk) {
      // active tiles: update + fused exact key recompute + winner-z store
#define UPD(J) if (msk & (1u << (J))) {                                   \
        const int sp_ = ((J) << 9) + t;                                   \
        const float2 v = XY[sp_];                                         \
        const float zz = ZS[sp_];                                         \
        const unsigned pp = PS[sp_];                                      \
        const float dx = v.x - lx, dy = v.y - ly, dz = zz - lz;           \
        const float d = ((dx * dx) + (dy * dy)) + (dz * dz);              \
        const float nd = fminf(dist[(J)], d);                             \
        dist[(J)] = nd;                                                   \
        unsigned kh = __float_as_uint(nd), kl = pp;                       \
        RED64(kh, kl)                                                     \
        const unsigned skh = (unsigned)__builtin_amdgcn_readlane((int)kh, 63); \
        const unsigned skl = (unsigned)__builtin_amdgcn_readlane((int)kl, 63); \
        if (pp == skl) tzL[w][(J)] = zz;                                  \
        if (lane == 63) { thL[w][(J)] = skh; tlL[w][(J)] = skl; } }
      UPD(0)  UPD(1)  UPD(2)  UPD(3)  UPD(4)  UPD(5)  UPD(6)  UPD(7)
      UPD(8)  UPD(9)  UPD(10) UPD(11) UPD(12) UPD(13) UPD(14) UPD(15)
      UPD(16) UPD(17) UPD(18) UPD(19) UPD(20) UPD(21) UPD(22) UPD(23)
      UPD(24) UPD(25) UPD(26) UPD(27) UPD(28) UPD(29) UPD(30) UPD(31)
#undef UPD
      // wave key over 32 cached tile keys (lanes 32-63 read duplicates)
      unsigned h = thL[w][l32], l2 = tlL[w][l32];
      RED64(h, l2)
      wkh = (unsigned)__builtin_amdgcn_readlane((int)h, 63);
      wkl = (unsigned)__builtin_amdgcn_readlane((int)l2, 63);
      zc = tzL[w][(wkl & 0x3FFFu) >> 9];        // own-wave LDS, no race
    }
    const int p = k & 1;
    if (lane == 0) {
      redk[p][w] = ((unsigned long long)wkh << 32) | wkl;
      redz[p][w] = zc;
    }
    __syncthreads();

    // cross-wave combine: 8 slots, LDS-only
    const unsigned long long kj = redk[p][lane & 7];
    unsigned h2 = (unsigned)(kj >> 32), l3 = (unsigned)kj;
    dpp_max64<0x111>(h2, l3);
    dpp_max64<0x112>(h2, l3);
    dpp_max64<0x114>(h2, l3);                   // lane 7 of each row = block max
    const unsigned kml = (unsigned)__builtin_amdgcn_readlane((int)l3, 7);
    const int sp = (int)(kml & 0x3FFFu);
    cur = (int)((kml >> 14) & 0x3FFFu) ^ 0x3FFF;
    const float2 sxy = XY[sp];                  // uniform LDS broadcast
    lx = sxy.x; ly = sxy.y;
    lz = redz[p][(sp >> 6) & 7];                // winner wave's z, LDS
    // one barrier/iter: parity double-buffer protects redk/redz
  }
}

// ---------------- Ball query ----------------
__global__ __launch_bounds__(256)
void ballq_kernel(const float* __restrict__ xyz, const int* __restrict__ fps_idx,
                  int* __restrict__ ball_idx)
{
#pragma clang fp contract(off)
  const int gw = (int)((blockIdx.x * blockDim.x + threadIdx.x) >> 6);
  const int lane = threadIdx.x & 63;
  const int b = gw >> 10, s = gw & 1023;
  const float* __restrict__ X = xyz + (size_t)b * NPTS * 3;
  const int ci = fps_idx[b * NP + s];
  const float cx = X[ci * 3 + 0], cy = X[ci * 3 + 1], cz = X[ci * 3 + 2];
  const float n2 = ((cx * cx) + (cy * cy)) + (cz * cz);
  int* __restrict__ out = ball_idx + (size_t)(b * NP + s) * NS;

  int cnt = 0;
  int first = -1;
  for (int c0 = 0; c0 < NPTS && cnt < NS; c0 += 64) {
    const int p = c0 + lane;
    const float x = X[p * 3 + 0], y = X[p * 3 + 1], z = X[p * 3 + 2];
    const float x2 = ((x * x) + (y * y)) + (z * z);
    const float dt = ((cx * x) + (cy * y)) + (cz * z);
    const float d2 = (n2 + x2) - (2.0f * dt);
    const bool inball = d2 < 0.04f;
    const unsigned long long mm = __ballot(inball);
    if (inball) {
      const int pos = cnt + __popcll(mm & ((1ull << lane) - 1ull));
      if (pos < NS) out[pos] = p;
    }
    if (first < 0 && mm != 0ull) first = c0 + __builtin_ctzll(mm);
    cnt += __popcll(mm);
  }
  if (cnt < NS) {
    if (first < 0) first = 0;
    if (lane >= cnt && lane < NS) out[lane] = first;
  }
}

// ---------------- Transpose feats [B][C][N] -> [B][N][C] ----------------
__global__ __launch_bounds__(256)
void transpose_kernel(const float* __restrict__ feats, float* __restrict__ featsT)
{
  __shared__ float t[32][33];
  const int b = blockIdx.z;
  const int cb = blockIdx.y * 32;
  const int nb = blockIdx.x * 32;
  const int tx = threadIdx.x;
  const int ty = threadIdx.y;
  const float* __restrict__ F = feats + (size_t)b * CIN * NPTS;
#pragma unroll
  for (int i = 0; i < 32; i += 8)
    t[ty + i][tx] = F[(size_t)(cb + ty + i) * NPTS + nb + tx];
  __syncthreads();
  float* __restrict__ FT_ = featsT + (size_t)b * NPTS * CIN;
#pragma unroll
  for (int i = 0; i < 32; i += 8)
    FT_[(size_t)(nb + ty + i) * CIN + cb + tx] = t[tx][ty + i];
}

// ---------------- Gather + max-pool ----------------
__global__ __launch_bounds__(128)
void pool_kernel(const float* __restrict__ featsT, const int* __restrict__ ball_idx,
                 float* __restrict__ pooled)
{
  const int bs = blockIdx.x;
  const int c = threadIdx.x;
  const int b = bs >> 10;
  const int* __restrict__ idx = ball_idx + (size_t)bs * NS;
  const float* __restrict__ FT_ = featsT + (size_t)b * NPTS * CIN;
  float m = -INFINITY;
#pragma unroll 4
  for (int k = 0; k < NS; ++k) {
    const int n = idx[k];
    m = fmaxf(m, FT_[(size_t)n * CIN + c]);
  }
  pooled[(size_t)bs * CIN + c] = m;
}

// ---------------- 1x1 conv + BN + LeakyReLU ----------------
#define GO 128
#define GS 64
__global__ __launch_bounds__(256, 1)
void gemm_kernel(const float* __restrict__ pooled, const float* __restrict__ W,
                 const float* __restrict__ gamma, const float* __restrict__ beta,
                 const float* __restrict__ mean, const float* __restrict__ var,
                 float* __restrict__ out)
{
  __shared__ float Wt[128 * 132];
  __shared__ float Pl[128 * 68];
  const int b = blockIdx.z;
  const int ob = blockIdx.y * GO;
  const int sb = blockIdx.x * GS;
  const int tid = threadIdx.x;

  for (int i = tid; i < GO * 128; i += 256) {
    const int o = i >> 7, c = i & 127;
    Wt[c * 132 + o] = W[(ob + o) * 128 + c];
  }
  const float* __restrict__ P = pooled + (size_t)(b * NP + sb) * 128;
  for (int i = tid; i < GS * 128; i += 256) {
    const int s = i >> 7, c = i & 127;
    Pl[c * 68 + s] = P[s * 128 + c];
  }
  __syncthreads();

  const int to = tid & 31, ts = tid >> 5;
  const int o0 = to * 4, s0 = ts * 8;
  float acc[4][8];
#pragma unroll
  for (int o = 0; o < 4; ++o)
#pragma unroll
    for (int j = 0; j < 8; ++j) acc[o][j] = 0.0f;

  for (int c = 0; c < 128; ++c) {
    const float4 wv = *(const float4*)&Wt[c * 132 + o0];
    const float4 pa = *(const float4*)&Pl[c * 68 + s0];
    const float4 pb = *(const float4*)&Pl[c * 68 + s0 + 4];
    const float wr[4] = {wv.x, wv.y, wv.z, wv.w};
    const float pr[8] = {pa.x, pa.y, pa.z, pa.w, pb.x, pb.y, pb.z, pb.w};
#pragma unroll
    for (int o = 0; o < 4; ++o)
#pragma unroll
      for (int j = 0; j < 8; ++j)
        acc[o][j] = fmaf(wr[o], pr[j], acc[o][j]);
  }

#pragma unroll
  for (int o = 0; o < 4; ++o) {
    const int oo = ob + o0 + o;
    const float sc = gamma[oo] / sqrtf(var[oo] + 1e-5f);
    const float sh = beta[oo] - mean[oo] * sc;
    float r[8];
#pragma unroll
    for (int j = 0; j < 8; ++j) {
      const float y = fmaf(acc[o][j], sc, sh);
      r[j] = (y >= 0.0f) ? y : 0.2f * y;
    }
    float* __restrict__ O = out + (size_t)(b * COUT + oo) * NP + sb + s0;
    *(float4*)&O[0] = make_float4(r[0], r[1], r[2], r[3]);
    *(float4*)&O[4] = make_float4(r[4], r[5], r[6], r[7]);
  }
}

// ---------------- launch ----------------
extern "C" void kernel_launch(void* const* d_in, const int* in_sizes, int n_in,
                              void* d_out, int out_size, void* d_ws, size_t ws_size,
                              hipStream_t stream)
{
  (void)in_sizes; (void)n_in; (void)out_size; (void)ws_size;
  const float* xyz   = (const float*)d_in[0];
  const float* feats = (const float*)d_in[1];
  const float* W     = (const float*)d_in[2];
  const float* gamma = (const float*)d_in[3];
  const float* beta  = (const float*)d_in[4];
  const float* mean  = (const float*)d_in[5];
  const float* var   = (const float*)d_in[6];
  float* out = (float*)d_out;

  char* ws = (char*)d_ws;
  // fps_idx [32KB] @0 | ball_idx [1MB] @32768 | featsT [64MB] @1081344 |
  // pooled [4MB] @68190208. Sort scratch aliases featsT head (dead before
  // transpose runs; stream order guarantees no overlap-in-time).
  int*   fps_idx  = (int*)(ws + 0);
  int*   ball_idx = (int*)(ws + 32768);
  char*  fbase    = ws + 1081344;
  float* featsT   = (float*)fbase;
  float* pooled   = (float*)(ws + 68190208);

  float2*   sxy2S  = (float2*)(fbase + 0);        // 1 MB
  float*    szS    = (float*)(fbase + 1048576);   // 512 KB
  unsigned* plS    = (unsigned*)(fbase + 1572864);// 512 KB
  int*      hist   = (int*)(fbase + 2097152);     // 16 KB
  int*      cursor = (int*)(fbase + 2113536);     // 16 KB

  zero_hist_kernel<<<NBATCH, NCELL, 0, stream>>>(hist);
  hist_kernel<<<(NBATCH * NPTS) / 256, 256, 0, stream>>>(xyz, hist);
  scan_kernel<<<NBATCH, NCELL, 0, stream>>>(hist, cursor);
  scatter_kernel<<<(NBATCH * NPTS) / 256, 256, 0, stream>>>(xyz, cursor, sxy2S, szS, plS);
  fps_kernel<<<NBATCH, FPS_T, 0, stream>>>(xyz, sxy2S, szS, plS, fps_idx);
  ballq_kernel<<<(NBATCH * NP) / 4, 256, 0, stream>>>(xyz, fps_idx, ball_idx);
  transpose_kernel<<<dim3(NPTS / 32, CIN / 32, NBATCH), dim3(32, 8), 0, stream>>>(feats, featsT);
  pool_kernel<<<NBATCH * NP, CIN, 0, stream>>>(featsT, ball_idx, pooled);
  gemm_kernel<<<dim3(NP / GS, COUT / GO, NBATCH), 256, 0, stream>>>(pooled, W, gamma, beta, mean, var, out);
}

// Round 13
// 1895.510 us; speedup vs baseline: 1.2727x; 1.2727x over previous
//
#include <hip/hip_runtime.h>
#include <math.h>

#define NPTS 16384
#define NBATCH 8
#define CIN 128
#define COUT 256
#define NP 1024
#define NS 32

#define NCELL 512     // 8x8x8 Morton cells
#define FPS_T 1024    // 16 waves, 4/SIMD

// ---------------- spatial sort preprocessing ----------------
__device__ __forceinline__ int cell_of(float x, float y, float z)
{
  int ix = (int)(x * 8.0f); ix = ix < 0 ? 0 : (ix > 7 ? 7 : ix);
  int iy = (int)(y * 8.0f); iy = iy < 0 ? 0 : (iy > 7 ? 7 : iy);
  int iz = (int)(z * 8.0f); iz = iz < 0 ? 0 : (iz > 7 ? 7 : iz);
  int m = 0;
#pragma unroll
  for (int b = 0; b < 3; ++b)
    m |= (((ix >> b) & 1) << (3 * b)) | (((iy >> b) & 1) << (3 * b + 1))
       | (((iz >> b) & 1) << (3 * b + 2));
  return m;
}

__global__ void zero_hist_kernel(int* __restrict__ hist)
{
  hist[blockIdx.x * NCELL + threadIdx.x] = 0;
}

__global__ void hist_kernel(const float* __restrict__ xyz, int* __restrict__ hist)
{
  const int i = blockIdx.x * 256 + threadIdx.x;
  const int b = i >> 14, n = i & (NPTS - 1);
  const float* p = xyz + ((size_t)b * NPTS + n) * 3;
  atomicAdd(&hist[b * NCELL + cell_of(p[0], p[1], p[2])], 1);
}

__global__ void scan_kernel(const int* __restrict__ hist, int* __restrict__ cursor)
{
  __shared__ int s[NCELL];
  const int b = blockIdx.x, t = threadIdx.x;
  const int h = hist[b * NCELL + t];
  s[t] = h;
  __syncthreads();
  for (int off = 1; off < NCELL; off <<= 1) {
    const int v = (t >= off) ? s[t - off] : 0;
    __syncthreads();
    s[t] += v;
    __syncthreads();
  }
  cursor[b * NCELL + t] = s[t] - h;   // exclusive
}

__global__ void scatter_kernel(const float* __restrict__ xyz, int* __restrict__ cursor,
                               float2* __restrict__ sxy2S, float* __restrict__ szS,
                               int* __restrict__ siS)
{
  const int i = blockIdx.x * 256 + threadIdx.x;
  const int b = i >> 14, n = i & (NPTS - 1);
  const float* p = xyz + ((size_t)b * NPTS + n) * 3;
  const float x = p[0], y = p[1], z = p[2];
  const int pos = atomicAdd(&cursor[b * NCELL + cell_of(x, y, z)], 1);
  const size_t o = (size_t)b * NPTS + pos;
  sxy2S[o] = make_float2(x, y);
  szS[o] = z;
  siS[o] = n;
}

// ---------------- DPP helpers ----------------
template <int CTRL>
__device__ __forceinline__ void dpp_max64(unsigned& hi, unsigned& lo)
{
  const unsigned ohi = (unsigned)__builtin_amdgcn_update_dpp((int)hi, (int)hi, CTRL, 0xF, 0xF, false);
  const unsigned olo = (unsigned)__builtin_amdgcn_update_dpp((int)lo, (int)lo, CTRL, 0xF, 0xF, false);
  const bool t = (ohi > hi) || (ohi == hi && olo > lo);
  hi = t ? ohi : hi;
  lo = t ? olo : lo;
}
template <int CTRL>
__device__ __forceinline__ float dppmaxf(float v)
{
  const float o = __uint_as_float((unsigned)__builtin_amdgcn_update_dpp(
      (int)__float_as_uint(v), (int)__float_as_uint(v), CTRL, 0xF, 0xF, false));
  return fmaxf(v, o);
}
template <int CTRL>
__device__ __forceinline__ float dppminf(float v)
{
  const float o = __uint_as_float((unsigned)__builtin_amdgcn_update_dpp(
      (int)__float_as_uint(v), (int)__float_as_uint(v), CTRL, 0xF, 0xF, false));
  return fminf(v, o);
}
#define RED6F(v) v = dppmaxf<0x111>(v); v = dppmaxf<0x112>(v); v = dppmaxf<0x114>(v); \
                 v = dppmaxf<0x118>(v); v = dppmaxf<0x142>(v); v = dppmaxf<0x143>(v);
#define RED6FN(v) v = dppminf<0x111>(v); v = dppminf<0x112>(v); v = dppminf<0x114>(v); \
                  v = dppminf<0x118>(v); v = dppminf<0x142>(v); v = dppminf<0x143>(v);
#define RED64_6(h, l) dpp_max64<0x111>(h, l); dpp_max64<0x112>(h, l); \
                      dpp_max64<0x114>(h, l); dpp_max64<0x118>(h, l); \
                      dpp_max64<0x142>(h, l); dpp_max64<0x143>(h, l);
#define RED64_4(h, l) dpp_max64<0x111>(h, l); dpp_max64<0x112>(h, l); \
                      dpp_max64<0x114>(h, l); dpp_max64<0x118>(h, l);

// ---------------- FPS ----------------
// 1 block/batch, 1024 thr (16 waves, 4/SIMD for latency hiding). Layout
// sp=(i<<10)+t: slot i of wave w = 64 CONSECUTIVE Morton pts (fine tile);
// adjacent tiles live on different waves (no chain serialization). Per-slot
// cull with slot bbox + cached slot key held in lane (lane&15)'s REGISTERS —
// test is register-only (round-11's LDS-read-in-test flaw fixed), 64-pt
// granularity (round-8's 1024-pt wave cull was ~40% active). 52-reg budget
// at 1024thr (measured cap): dist[16]+pidp[8]+bbox6+key2 fits; z is NOT
// register-resident — re-loaded (coalesced, XCD-L2-hot) only in active-slot
// UPDs where 4 waves/SIMD hide it. Fused exact u64 key (maxdist|invpid|spos)
// per updated slot; wave key = RED64-4 over 16 cached lane keys (no LDS).
// Tie-break exact (max invpid = min original idx). 1 barrier/iter, parity.
__global__ __launch_bounds__(FPS_T)
void fps_kernel(const float* __restrict__ xyz,
                const float2* __restrict__ sxy2S, const float* __restrict__ szS,
                const int* __restrict__ siS, int* __restrict__ fps_idx)
{
#pragma clang fp contract(off)
  __shared__ float2 XY[NPTS];                   // 128 KB, sorted order
  __shared__ unsigned long long redk[2][16];
  const int b = blockIdx.x;
  const int t = threadIdx.x;
  const int lane = t & 63, w = t >> 6;
  const int j16 = lane & 15;
  const float* __restrict__ X = xyz + (size_t)b * NPTS * 3;
  const float* __restrict__ ZS = szS + (size_t)b * NPTS;
  const int* __restrict__ IS = siS + (size_t)b * NPTS;
  const float2* __restrict__ XYS = sxy2S + (size_t)b * NPTS;

  float dist[16];
  int pidp[8];                                  // 2x invpid (14b) per u32
  float cbxn = 0, cbxx = 0, cbyn = 0, cbyx = 0, cbzn = 0, cbzx = 0;  // slot j16 bbox
  unsigned ckh = __float_as_uint(1e10f), ckl = 0;                    // slot j16 key
  unsigned tmpinv = 0;
#pragma unroll
  for (int i = 0; i < 16; ++i) {
    const int sp = (i << 10) + t;
    const float2 v = XYS[sp];                   // coalesced
    XY[sp] = v;                                 // conflict-free ds_write_b64
    const float zz = ZS[sp];                    // coalesced
    const unsigned inv = (unsigned)(IS[sp] ^ 0x3FFF);
    if ((i & 1) == 0) tmpinv = inv; else pidp[i >> 1] = (int)(tmpinv | (inv << 16));
    dist[i] = 1e10f;
    // slot bbox (RED6 over this wave's 64 lanes) + initial key (uniform dist)
    float xn = v.x, xx = v.x, yn = v.y, yx = v.y, zn = zz, zx = zz;
    RED6FN(xn) RED6F(xx) RED6FN(yn) RED6F(yx) RED6FN(zn) RED6F(zx)
    unsigned kh0 = __float_as_uint(1e10f), kl0 = (inv << 14) | (unsigned)sp;
    RED64_6(kh0, kl0)
    const float sxn = __uint_as_float((unsigned)__builtin_amdgcn_readlane(__float_as_int(xn), 63));
    const float sxx = __uint_as_float((unsigned)__builtin_amdgcn_readlane(__float_as_int(xx), 63));
    const float syn = __uint_as_float((unsigned)__builtin_amdgcn_readlane(__float_as_int(yn), 63));
    const float syx = __uint_as_float((unsigned)__builtin_amdgcn_readlane(__float_as_int(yx), 63));
    const float szn = __uint_as_float((unsigned)__builtin_amdgcn_readlane(__float_as_int(zn), 63));
    const float szx = __uint_as_float((unsigned)__builtin_amdgcn_readlane(__float_as_int(zx), 63));
    const unsigned skl = (unsigned)__builtin_amdgcn_readlane((int)kl0, 63);
    if (j16 == i) {
      cbxn = sxn; cbxx = sxx; cbyn = syn; cbyx = syx; cbzn = szn; cbzx = szx;
      ckl = skl;                                // ckh already 1e10 bits
    }
  }
  __syncthreads();

  unsigned wkh = __float_as_uint(1e10f), wkl = 0;  // cached wave key
  int cur = 0;
  float lx = X[0], ly = X[1], lz = X[2];

  for (int k = 0; k < NP; ++k) {
    if (t == 0) fps_idx[b * NP + k] = cur;

    // lane (any row) tests slot (lane&15) — register-only exact skip
    const float ddx = fmaxf(fmaxf(cbxn - lx, lx - cbxx), 0.0f);
    const float ddy = fmaxf(fmaxf(cbyn - ly, ly - cbyx), 0.0f);
    const float ddz = fmaxf(fmaxf(cbzn - lz, lz - cbzx), 0.0f);
    const float db2 = ((ddx * ddx) + (ddy * ddy)) + (ddz * ddz);
    const bool act = db2 <= __uint_as_float(ckh) * 1.00001f;
    const unsigned msk = __builtin_amdgcn_readfirstlane(
        (unsigned)__ballot(act) & 0xFFFFu);     // row 0's 16 slot bits

    if (msk) {
      // active slots: update + fused exact key recompute; z re-loaded from
      // L2-hot ZS (not register-resident: 52-reg cap at 1024thr)
#define UPD(J) if (msk & (1u << (J))) {                                   \
        const int sp_ = ((J) << 10) + t;                                  \
        const float2 v = XY[sp_];                                         \
        const float zz = ZS[sp_];                                         \
        const float dx = v.x - lx, dy = v.y - ly, dz = zz - lz;           \
        const float d = ((dx * dx) + (dy * dy)) + (dz * dz);              \
        const float nd = fminf(dist[(J)], d);                             \
        dist[(J)] = nd;                                                   \
        const unsigned inv = ((unsigned)pidp[(J) >> 1] >> (((J) & 1) * 16)) & 0xFFFFu; \
        unsigned kh = __float_as_uint(nd), kl = (inv << 14) | (unsigned)sp_; \
        RED64_6(kh, kl)                                                   \
        const unsigned skh = (unsigned)__builtin_amdgcn_readlane((int)kh, 63); \
        const unsigned skl = (unsigned)__builtin_amdgcn_readlane((int)kl, 63); \
        if (j16 == (J)) { ckh = skh; ckl = skl; } }
      UPD(0)  UPD(1)  UPD(2)  UPD(3)  UPD(4)  UPD(5)  UPD(6)  UPD(7)
      UPD(8)  UPD(9)  UPD(10) UPD(11) UPD(12) UPD(13) UPD(14) UPD(15)
#undef UPD
      // wave key over the 16 cached slot keys (each 16-lane row reduces its
      // duplicate copy; row 0's lane 15 read back)
      unsigned h = ckh, l2 = ckl;
      RED64_4(h, l2)
      wkh = (unsigned)__builtin_amdgcn_readlane((int)h, 15);
      wkl = (unsigned)__builtin_amdgcn_readlane((int)l2, 15);
    }
    const int p = k & 1;
    if (lane == 0)
      redk[p][w] = ((unsigned long long)wkh << 32) | wkl;
    __syncthreads();

    // cross-wave combine; speculative winner-z load overlaps the DPP chain
    const unsigned long long kj = redk[p][j16];
    const unsigned shi = (unsigned)(kj >> 32), slo = (unsigned)kj;
    const float sgz = ZS[(int)(slo & 0x3FFFu)]; // global (L2), overlapped
    unsigned h2 = shi, l3 = slo;
    RED64_4(h2, l3)                             // lane 15 of each row = block max
    const unsigned kmh = (unsigned)__builtin_amdgcn_readlane((int)h2, 15);
    const unsigned kml = (unsigned)__builtin_amdgcn_readlane((int)l3, 15);
    cur = (int)((kml >> 14) & 0x3FFFu) ^ 0x3FFF;
    const unsigned long long tmsk = __ballot(shi == kmh && slo == kml);
    const int bwl = (int)__builtin_ctzll(tmsk);
    lz = __uint_as_float((unsigned)__builtin_amdgcn_readlane(__float_as_int(sgz), bwl));
    const float2 sxy = XY[(int)(kml & 0x3FFFu)];  // uniform LDS broadcast read
    lx = sxy.x; ly = sxy.y;
    // one barrier/iter: parity double-buffer makes overwrite-while-read impossible
  }
}

// ---------------- Ball query ----------------
__global__ __launch_bounds__(256)
void ballq_kernel(const float* __restrict__ xyz, const int* __restrict__ fps_idx,
                  int* __restrict__ ball_idx)
{
#pragma clang fp contract(off)
  const int gw = (int)((blockIdx.x * blockDim.x + threadIdx.x) >> 6);
  const int lane = threadIdx.x & 63;
  const int b = gw >> 10, s = gw & 1023;
  const float* __restrict__ X = xyz + (size_t)b * NPTS * 3;
  const int ci = fps_idx[b * NP + s];
  const float cx = X[ci * 3 + 0], cy = X[ci * 3 + 1], cz = X[ci * 3 + 2];
  const float n2 = ((cx * cx) + (cy * cy)) + (cz * cz);
  int* __restrict__ out = ball_idx + (size_t)(b * NP + s) * NS;

  int cnt = 0;
  int first = -1;
  for (int c0 = 0; c0 < NPTS && cnt < NS; c0 += 64) {
    const int p = c0 + lane;
    const float x = X[p * 3 + 0], y = X[p * 3 + 1], z = X[p * 3 + 2];
    const float x2 = ((x * x) + (y * y)) + (z * z);
    const float dt = ((cx * x) + (cy * y)) + (cz * z);
    const float d2 = (n2 + x2) - (2.0f * dt);
    const bool inball = d2 < 0.04f;
    const unsigned long long mm = __ballot(inball);
    if (inball) {
      const int pos = cnt + __popcll(mm & ((1ull << lane) - 1ull));
      if (pos < NS) out[pos] = p;
    }
    if (first < 0 && mm != 0ull) first = c0 + __builtin_ctzll(mm);
    cnt += __popcll(mm);
  }
  if (cnt < NS) {
    if (first < 0) first = 0;
    if (lane >= cnt && lane < NS) out[lane] = first;
  }
}

// ---------------- Transpose feats [B][C][N] -> [B][N][C] ----------------
__global__ __launch_bounds__(256)
void transpose_kernel(const float* __restrict__ feats, float* __restrict__ featsT)
{
  __shared__ float t[32][33];
  const int b = blockIdx.z;
  const int cb = blockIdx.y * 32;
  const int nb = blockIdx.x * 32;
  const int tx = threadIdx.x;
  const int ty = threadIdx.y;
  const float* __restrict__ F = feats + (size_t)b * CIN * NPTS;
#pragma unroll
  for (int i = 0; i < 32; i += 8)
    t[ty + i][tx] = F[(size_t)(cb + ty + i) * NPTS + nb + tx];
  __syncthreads();
  float* __restrict__ FT_ = featsT + (size_t)b * NPTS * CIN;
#pragma unroll
  for (int i = 0; i < 32; i += 8)
    FT_[(size_t)(nb + ty + i) * CIN + cb + tx] = t[tx][ty + i];
}

// ---------------- Gather + max-pool ----------------
__global__ __launch_bounds__(128)
void pool_kernel(const float* __restrict__ featsT, const int* __restrict__ ball_idx,
                 float* __restrict__ pooled)
{
  const int bs = blockIdx.x;
  const int c = threadIdx.x;
  const int b = bs >> 10;
  const int* __restrict__ idx = ball_idx + (size_t)bs * NS;
  const float* __restrict__ FT_ = featsT + (size_t)b * NPTS * CIN;
  float m = -INFINITY;
#pragma unroll 4
  for (int k = 0; k < NS; ++k) {
    const int n = idx[k];
    m = fmaxf(m, FT_[(size_t)n * CIN + c]);
  }
  pooled[(size_t)bs * CIN + c] = m;
}

// ---------------- 1x1 conv + BN + LeakyReLU ----------------
#define GO 128
#define GS 64
__global__ __launch_bounds__(256, 1)
void gemm_kernel(const float* __restrict__ pooled, const float* __restrict__ W,
                 const float* __restrict__ gamma, const float* __restrict__ beta,
                 const float* __restrict__ mean, const float* __restrict__ var,
                 float* __restrict__ out)
{
  __shared__ float Wt[128 * 132];
  __shared__ float Pl[128 * 68];
  const int b = blockIdx.z;
  const int ob = blockIdx.y * GO;
  const int sb = blockIdx.x * GS;
  const int tid = threadIdx.x;

  for (int i = tid; i < GO * 128; i += 256) {
    const int o = i >> 7, c = i & 127;
    Wt[c * 132 + o] = W[(ob + o) * 128 + c];
  }
  const float* __restrict__ P = pooled + (size_t)(b * NP + sb) * 128;
  for (int i = tid; i < GS * 128; i += 256) {
    const int s = i >> 7, c = i & 127;
    Pl[c * 68 + s] = P[s * 128 + c];
  }
  __syncthreads();

  const int to = tid & 31, ts = tid >> 5;
  const int o0 = to * 4, s0 = ts * 8;
  float acc[4][8];
#pragma unroll
  for (int o = 0; o < 4; ++o)
#pragma unroll
    for (int j = 0; j < 8; ++j) acc[o][j] = 0.0f;

  for (int c = 0; c < 128; ++c) {
    const float4 wv = *(const float4*)&Wt[c * 132 + o0];
    const float4 pa = *(const float4*)&Pl[c * 68 + s0];
    const float4 pb = *(const float4*)&Pl[c * 68 + s0 + 4];
    const float wr[4] = {wv.x, wv.y, wv.z, wv.w};
    const float pr[8] = {pa.x, pa.y, pa.z, pa.w, pb.x, pb.y, pb.z, pb.w};
#pragma unroll
    for (int o = 0; o < 4; ++o)
#pragma unroll
      for (int j = 0; j < 8; ++j)
        acc[o][j] = fmaf(wr[o], pr[j], acc[o][j]);
  }

#pragma unroll
  for (int o = 0; o < 4; ++o) {
    const int oo = ob + o0 + o;
    const float sc = gamma[oo] / sqrtf(var[oo] + 1e-5f);
    const float sh = beta[oo] - mean[oo] * sc;
    float r[8];
#pragma unroll
    for (int j = 0; j < 8; ++j) {
      const float y = fmaf(acc[o][j], sc, sh);
      r[j] = (y >= 0.0f) ? y : 0.2f * y;
    }
    float* __restrict__ O = out + (size_t)(b * COUT + oo) * NP + sb + s0;
    *(float4*)&O[0] = make_float4(r[0], r[1], r[2], r[3]);
    *(float4*)&O[4] = make_float4(r[4], r[5], r[6], r[7]);
  }
}

// ---------------- launch ----------------
extern "C" void kernel_launch(void* const* d_in, const int* in_sizes, int n_in,
                              void* d_out, int out_size, void* d_ws, size_t ws_size,
                              hipStream_t stream)
{
  (void)in_sizes; (void)n_in; (void)out_size; (void)ws_size;
  const float* xyz   = (const float*)d_in[0];
  const float* feats = (const float*)d_in[1];
  const float* W     = (const float*)d_in[2];
  const float* gamma = (const float*)d_in[3];
  const float* beta  = (const float*)d_in[4];
  const float* mean  = (const float*)d_in[5];
  const float* var   = (const float*)d_in[6];
  float* out = (float*)d_out;

  char* ws = (char*)d_ws;
  // fps_idx [32KB] @0 | ball_idx [1MB] @32768 | featsT [64MB] @1081344 |
  // pooled [4MB] @68190208. Sort scratch aliases featsT head (dead before
  // transpose runs; stream order guarantees no overlap-in-time).
  int*   fps_idx  = (int*)(ws + 0);
  int*   ball_idx = (int*)(ws + 32768);
  char*  fbase    = ws + 1081344;
  float* featsT   = (float*)fbase;
  float* pooled   = (float*)(ws + 68190208);

  float2* sxy2S  = (float2*)(fbase + 0);        // 1 MB
  float*  szS    = (float*)(fbase + 1048576);   // 512 KB
  int*    siS    = (int*)(fbase + 1572864);     // 512 KB
  int*    hist   = (int*)(fbase + 2097152);     // 16 KB
  int*    cursor = (int*)(fbase + 2113536);     // 16 KB

  zero_hist_kernel<<<NBATCH, NCELL, 0, stream>>>(hist);
  hist_kernel<<<(NBATCH * NPTS) / 256, 256, 0, stream>>>(xyz, hist);
  scan_kernel<<<NBATCH, NCELL, 0, stream>>>(hist, cursor);
  scatter_kernel<<<(NBATCH * NPTS) / 256, 256, 0, stream>>>(xyz, cursor, sxy2S, szS, siS);
  fps_kernel<<<NBATCH, FPS_T, 0, stream>>>(xyz, sxy2S, szS, siS, fps_idx);
  ballq_kernel<<<(NBATCH * NP) / 4, 256, 0, stream>>>(xyz, fps_idx, ball_idx);
  transpose_kernel<<<dim3(NPTS / 32, CIN / 32, NBATCH), dim3(32, 8), 0, stream>>>(feats, featsT);
  pool_kernel<<<NBATCH * NP, CIN, 0, stream>>>(featsT, ball_idx, pooled);
  gemm_kernel<<<dim3(NP / GS, COUT / GO, NBATCH), 256, 0, stream>>>(pooled, W, gamma, beta, mean, var, out);
}